// Round 1
// baseline (173.233 us; speedup 1.0000x reference)
//
#include <hip/hip_runtime.h>
#include <hip/hip_bf16.h>
#include <math.h>

#define NV 778
#define NJ 16
#define NCOMP 24
#define NBETA 10
#define FC 1554
#define NA 32
#define NB 8
#define NOBJ 16384

__constant__ int c_parents[NJ] = {-1,0,1,2,0,4,5,0,7,8,0,10,11,0,13,14};

// ---------------- Kernel 1: PCA -> Rodrigues -> pose_feat (one block per batch)
__global__ void k_pose(const float* __restrict__ hp, const float* __restrict__ pca,
                       float* __restrict__ Rws, float* __restrict__ PF, float* __restrict__ pen)
{
    int b = blockIdx.x, t = threadIdx.x;
    __shared__ float h45[45];
    __shared__ float sR[NJ * 9];
    if (t < 45) {
        float acc = 0.0f;
        for (int k = 0; k < NCOMP; ++k) acc += hp[b*30 + 6 + k] * pca[k*45 + t];
        h45[t] = acc;
    }
    __syncthreads();
    if (t < NJ) {
        float rx, ry, rz;
        if (t == 0) { rx = hp[b*30+3]; ry = hp[b*30+4]; rz = hp[b*30+5]; }
        else        { rx = h45[(t-1)*3]; ry = h45[(t-1)*3+1]; rz = h45[(t-1)*3+2]; }
        float th = sqrtf(rx*rx + ry*ry + rz*rz + 1e-16f);
        float kx = rx/th, ky = ry/th, kz = rz/th;
        float c = cosf(th), s = sinf(th), o = 1.0f - c;
        float R[9];
        R[0] = c + o*kx*kx;      R[1] = -s*kz + o*kx*ky;  R[2] =  s*ky + o*kx*kz;
        R[3] =  s*kz + o*ky*kx;  R[4] = c + o*ky*ky;      R[5] = -s*kx + o*ky*kz;
        R[6] = -s*ky + o*kz*kx;  R[7] =  s*kx + o*kz*ky;  R[8] = c + o*kz*kz;
        for (int i = 0; i < 9; ++i) { sR[t*9+i] = R[i]; Rws[b*(NJ*9) + t*9 + i] = R[i]; }
    }
    __syncthreads();
    for (int e = t; e < (NJ-1)*9; e += blockDim.x) {
        int j = e/9 + 1, mn = e%9;
        float d = (mn == 0 || mn == 4 || mn == 8) ? 1.0f : 0.0f;
        PF[b*135 + e] = sR[j*9 + mn] - d;
    }
    if (b == 0 && t == 0) *pen = 0.0f;   // init penetration accumulator (d_out is poisoned)
}

// ---------------- Kernel 2: v_shaped + v_posed
__global__ void k_blend(const float* __restrict__ vt, const float* __restrict__ sd,
                        const float* __restrict__ pd, const float* __restrict__ beta,
                        const float* __restrict__ PF, float* __restrict__ VS, float* __restrict__ VP)
{
    int i = blockIdx.x * blockDim.x + threadIdx.x;
    if (i >= NB * NV) return;
    int b = i / NV, v = i % NV;
    const float* bb = beta + b * NBETA;
    const float* pf = PF + b * 135;
    #pragma unroll
    for (int d = 0; d < 3; ++d) {
        float vs = vt[v*3 + d];
        const float* s = sd + v*3*NBETA + d*NBETA;
        #pragma unroll
        for (int k = 0; k < NBETA; ++k) vs += s[k] * bb[k];
        float vp = vs;
        const float* p = pd + v*3*135 + d*135;
        for (int k = 0; k < 135; ++k) vp += p[k] * pf[k];
        VS[i*3 + d] = vs;
        VP[i*3 + d] = vp;
    }
}

// ---------------- Kernel 3: joints J = J_regressor @ v_shaped (one wave per (b,j))
__global__ void k_joints(const float* __restrict__ Jreg, const float* __restrict__ VS,
                         float* __restrict__ Jws)
{
    int blk = blockIdx.x;
    int b = blk >> 4, j = blk & 15, t = threadIdx.x;
    float a0 = 0, a1 = 0, a2 = 0;
    for (int v = t; v < NV; v += 64) {
        float w = Jreg[j*NV + v];
        const float* p = VS + (b*NV + v)*3;
        a0 += w * p[0]; a1 += w * p[1]; a2 += w * p[2];
    }
    for (int off = 32; off; off >>= 1) {
        a0 += __shfl_down(a0, off, 64);
        a1 += __shfl_down(a1, off, 64);
        a2 += __shfl_down(a2, off, 64);
    }
    if (t == 0) {
        Jws[(b*NJ + j)*3 + 0] = a0;
        Jws[(b*NJ + j)*3 + 1] = a1;
        Jws[(b*NJ + j)*3 + 2] = a2;
    }
}

// ---------------- Kernel 4: kinematic chain + A matrices (one thread per batch)
__global__ void k_chain(const float* __restrict__ Rws, const float* __restrict__ Jws,
                        float* __restrict__ Aws)
{
    int b = threadIdx.x;
    if (b >= NB) return;
    __shared__ float TR[NB][NJ][9];
    __shared__ float Tt[NB][NJ][3];
    const float* Rb = Rws + b * NJ * 9;
    const float* Jb = Jws + b * NJ * 3;
    for (int i = 0; i < 9; ++i) TR[b][0][i] = Rb[i];
    for (int d = 0; d < 3; ++d) Tt[b][0][d] = Jb[d];
    for (int j = 1; j < NJ; ++j) {
        int p = c_parents[j];
        float t0 = Jb[j*3+0] - Jb[p*3+0];
        float t1 = Jb[j*3+1] - Jb[p*3+1];
        float t2 = Jb[j*3+2] - Jb[p*3+2];
        const float* Rj = Rb + j*9;
        for (int m = 0; m < 3; ++m) {
            float pm0 = TR[b][p][m*3+0], pm1 = TR[b][p][m*3+1], pm2 = TR[b][p][m*3+2];
            for (int n = 0; n < 3; ++n)
                TR[b][j][m*3+n] = pm0*Rj[n] + pm1*Rj[3+n] + pm2*Rj[6+n];
            Tt[b][j][m] = pm0*t0 + pm1*t1 + pm2*t2 + Tt[b][p][m];
        }
    }
    for (int j = 0; j < NJ; ++j) {
        float jx = Jb[j*3], jy = Jb[j*3+1], jz = Jb[j*3+2];
        for (int m = 0; m < 3; ++m) {
            float r0 = TR[b][j][m*3+0], r1 = TR[b][j][m*3+1], r2 = TR[b][j][m*3+2];
            float corr = r0*jx + r1*jy + r2*jz;
            Aws[b*NJ*12 + j*12 + m*4 + 0] = r0;
            Aws[b*NJ*12 + j*12 + m*4 + 1] = r1;
            Aws[b*NJ*12 + j*12 + m*4 + 2] = r2;
            Aws[b*NJ*12 + j*12 + m*4 + 3] = Tt[b][j][m] - corr;
        }
    }
}

// ---------------- Kernel 5: LBS + trans -> verts (d_out region) + |v|^2
__global__ void k_lbs(const float* __restrict__ W, const float* __restrict__ Aws,
                      const float* __restrict__ VP, const float* __restrict__ hp,
                      float* __restrict__ verts, float* __restrict__ VSQ)
{
    int i = blockIdx.x * blockDim.x + threadIdx.x;
    if (i >= NB * NV) return;
    int b = i / NV, v = i % NV;
    float acc[12];
    #pragma unroll
    for (int q = 0; q < 12; ++q) acc[q] = 0.0f;
    const float* w = W + v * NJ;
    const float* A = Aws + b * NJ * 12;
    for (int j = 0; j < NJ; ++j) {
        float wj = w[j];
        #pragma unroll
        for (int q = 0; q < 12; ++q) acc[q] += wj * A[j*12 + q];
    }
    float px = VP[i*3], py = VP[i*3+1], pz = VP[i*3+2];
    float x = acc[0]*px + acc[1]*py + acc[2]*pz  + acc[3]  + hp[b*30+0];
    float y = acc[4]*px + acc[5]*py + acc[6]*pz  + acc[7]  + hp[b*30+1];
    float z = acc[8]*px + acc[9]*py + acc[10]*pz + acc[11] + hp[b*30+2];
    verts[i*3+0] = x; verts[i*3+1] = y; verts[i*3+2] = z;
    VSQ[i] = x*x + y*y + z*z;
}

// ---------------- Kernel 6: zero normals accumulator
__global__ void k_zero(float* __restrict__ p, int n)
{
    int i = blockIdx.x * blockDim.x + threadIdx.x;
    if (i < n) p[i] = 0.0f;
}

// ---------------- Kernel 7: face normals scatter
__global__ void k_faces(const int* __restrict__ faces, const float* __restrict__ verts,
                        float* __restrict__ NRM)
{
    int i = blockIdx.x * blockDim.x + threadIdx.x;
    if (i >= NB * FC) return;
    int b = i / FC, f = i % FC;
    int i0 = faces[f*3], i1 = faces[f*3+1], i2 = faces[f*3+2];
    const float* vb = verts + b * NV * 3;
    float ax = vb[i1*3+0] - vb[i0*3+0], ay = vb[i1*3+1] - vb[i0*3+1], az = vb[i1*3+2] - vb[i0*3+2];
    float bx = vb[i2*3+0] - vb[i0*3+0], by = vb[i2*3+1] - vb[i0*3+1], bz = vb[i2*3+2] - vb[i0*3+2];
    float cx = ay*bz - az*by, cy = az*bx - ax*bz, cz = ax*by - ay*bx;
    float* nb = NRM + b * NV * 3;
    atomicAdd(&nb[i0*3+0], cx); atomicAdd(&nb[i0*3+1], cy); atomicAdd(&nb[i0*3+2], cz);
    atomicAdd(&nb[i1*3+0], cx); atomicAdd(&nb[i1*3+1], cy); atomicAdd(&nb[i1*3+2], cz);
    atomicAdd(&nb[i2*3+0], cx); atomicAdd(&nb[i2*3+1], cy); atomicAdd(&nb[i2*3+2], cz);
}

// ---------------- Kernel 8: normalize vertex normals in place
__global__ void k_nrm(float* __restrict__ NRM)
{
    int i = blockIdx.x * blockDim.x + threadIdx.x;
    if (i >= NB * NV) return;
    float x = NRM[i*3], y = NRM[i*3+1], z = NRM[i*3+2];
    float inv = 1.0f / (sqrtf(x*x + y*y + z*z) + 1e-8f);
    NRM[i*3] = x*inv; NRM[i*3+1] = y*inv; NRM[i*3+2] = z*inv;
}

// ---------------- Kernel 9: NN search + cmap + penetration
__global__ __launch_bounds__(256) void k_nn(const float* __restrict__ obj,
                                            const float* __restrict__ verts,
                                            const float* __restrict__ VSQ,
                                            const float* __restrict__ NRM,
                                            float* __restrict__ cmap,
                                            float* __restrict__ pen)
{
    __shared__ float4 sv[NV];
    int b = blockIdx.x >> 6;                  // 64 chunks of 256 per batch
    int n = (blockIdx.x & 63) * 256 + threadIdx.x;
    int t = threadIdx.x;
    for (int v = t; v < NV; v += 256) {
        const float* p = verts + (b*NV + v)*3;
        sv[v] = make_float4(p[0], p[1], p[2], VSQ[b*NV + v]);
    }
    __syncthreads();
    const float* o = obj + (b*NOBJ + n)*3;
    float ox = o[0], oy = o[1], oz = o[2];
    float osq = ox*ox + oy*oy + oz*oz;
    float best = 1e30f;
    int bi = 0;
    for (int v = 0; v < NV; ++v) {
        float4 q = sv[v];
        float d = osq + q.w - 2.0f * (ox*q.x + oy*q.y + oz*q.z);
        if (d < best) { best = d; bi = v; }
    }
    // cmap = 1 - 2*(sigmoid(100 d) - 0.5) = 2 / (1 + e^{100 d})
    cmap[b*NOBJ + n] = 2.0f / (1.0f + expf(100.0f * best));
    float4 q = sv[bi];
    float nx = NRM[(b*NV + bi)*3 + 0];
    float ny = NRM[(b*NV + bi)*3 + 1];
    float nz = NRM[(b*NV + bi)*3 + 2];
    float dotp = (q.x - ox)*nx + (q.y - oy)*ny + (q.z - oz)*nz;
    float p = (dotp > 0.0f) ? best : 0.0f;
    // block reduction: wave shuffle then cross-wave LDS
    for (int off = 32; off; off >>= 1) p += __shfl_down(p, off, 64);
    __shared__ float wsum[4];
    if ((t & 63) == 0) wsum[t >> 6] = p;
    __syncthreads();
    if (t == 0) atomicAdd(pen, (wsum[0] + wsum[1] + wsum[2] + wsum[3]) * (1.0f / NB));
}

// ---------------- Kernel 10: contact candidates
__global__ void k_contact(const float* __restrict__ aw, const int* __restrict__ afi,
                          const float* __restrict__ verts, float* __restrict__ out)
{
    int i = blockIdx.x * blockDim.x + threadIdx.x;
    if (i >= NB * NA * 3) return;
    int b = i / (NA*3);
    int r = i % (NA*3);
    int a = r / 3, d = r % 3;
    float acc = 0.0f;
    #pragma unroll
    for (int k = 0; k < 3; ++k) {
        int vi = afi[a*3 + k];
        acc += aw[a*3 + k] * verts[(b*NV + vi)*3 + d];
    }
    out[i] = acc;
}

extern "C" void kernel_launch(void* const* d_in, const int* in_sizes, int n_in,
                              void* d_out, int out_size, void* d_ws, size_t ws_size,
                              hipStream_t stream)
{
    const float* hp    = (const float*)d_in[0];   // hand_pose (B,30)
    const float* obj   = (const float*)d_in[1];   // obj_points (B,NOBJ,3)
    const float* beta  = (const float*)d_in[2];   // hand_beta (B,10)
    const float* vt    = (const float*)d_in[3];   // v_template (V,3)
    const float* sd    = (const float*)d_in[4];   // shapedirs (V,3,10)
    const float* pd    = (const float*)d_in[5];   // posedirs (V,3,135)
    const float* Jreg  = (const float*)d_in[6];   // J_regressor (16,V)
    const float* W     = (const float*)d_in[7];   // lbs_weights (V,16)
    const float* pca   = (const float*)d_in[8];   // pca_comps (24,45)
    const float* aw    = (const float*)d_in[9];   // anchor_weights (32,3)
    const int*   faces = (const int*)d_in[10];    // closed_faces (1554,3)
    const int*   afi   = (const int*)d_in[11];    // anchor_face_idx (32,3)

    float* out     = (float*)d_out;
    float* cmap    = out;                          // 8*16384 = 131072
    float* pen     = out + NB*NOBJ;                // 1
    float* verts   = out + NB*NOBJ + 1;            // 8*778*3 = 18672
    float* contact = out + NB*NOBJ + 1 + NB*NV*3;  // 768

    float* ws  = (float*)d_ws;
    float* Rws = ws;                 // B*16*9  = 1152
    float* PF  = Rws + NB*NJ*9;      // B*135   = 1080
    float* VS  = PF  + NB*135;       // B*V*3   = 18672
    float* VP  = VS  + NB*NV*3;      // B*V*3   = 18672
    float* Jws = VP  + NB*NV*3;      // B*16*3  = 384
    float* Aws = Jws + NB*NJ*3;      // B*16*12 = 1536
    float* VSQ = Aws + NB*NJ*12;     // B*V     = 6224
    float* NRM = VSQ + NB*NV;        // B*V*3   = 18672

    k_pose   <<<NB, 64, 0, stream>>>(hp, pca, Rws, PF, pen);
    k_blend  <<<(NB*NV + 255)/256, 256, 0, stream>>>(vt, sd, pd, beta, PF, VS, VP);
    k_joints <<<NB*NJ, 64, 0, stream>>>(Jreg, VS, Jws);
    k_chain  <<<1, 64, 0, stream>>>(Rws, Jws, Aws);
    k_lbs    <<<(NB*NV + 255)/256, 256, 0, stream>>>(W, Aws, VP, hp, verts, VSQ);
    k_zero   <<<(NB*NV*3 + 255)/256, 256, 0, stream>>>(NRM, NB*NV*3);
    k_faces  <<<(NB*FC + 255)/256, 256, 0, stream>>>(faces, verts, NRM);
    k_nrm    <<<(NB*NV + 255)/256, 256, 0, stream>>>(NRM);
    k_nn     <<<NB*64, 256, 0, stream>>>(obj, verts, VSQ, NRM, cmap, pen);
    k_contact<<<3, 256, 0, stream>>>(aw, afi, verts, contact);
}